// Round 12
// baseline (345.657 us; speedup 1.0000x reference)
//
#include <hip/hip_runtime.h>
#include <math.h>

#define V 32000
#define T 128
#define DD 64
#define NN 512
#define TCH 16   // t-chunk per k_energy_kl block

typedef float f32x4 __attribute__((ext_vector_type(4)));  // native vec for nontemporal builtin

constexpr float kB     = 1.4142135623730951f;   // sqrt(2)
constexpr float kLSLO  = -2.302585092994046f;   // log(0.1)
constexpr float kLSHI  =  2.302585092994046f;   // log(10)
constexpr float kLN2   =  0.6931471805599453f;
constexpr float kDLOG2PI = 117.6241322501981f;  // 64 * log(2*pi)

__device__ __forceinline__ float clampf(float x, float lo, float hi) {
    return fminf(fmaxf(x, lo), hi);
}

// ---------------------------------------------------------------- K0: prep T-side
// One wave per t: d = lane (D == wave size = 64). Coalesced, shuffle-reduced.
__global__ void k_prep(const float* __restrict__ mu_c, const float* __restrict__ ls_c,
                       float* __restrict__ st_td, float* __restrict__ mc_td,
                       float* __restrict__ rs_td, float* __restrict__ sumlsc) {
    const int t = blockIdx.x;
    const int d = threadIdx.x;
    float lc = clampf(ls_c[t * DD + d], kLSLO, kLSHI);
    const float st = __expf(lc);
    st_td[t * DD + d] = st;
    rs_td[t * DD + d] = 1.0f / st;
    mc_td[t * DD + d] = clampf(mu_c[t * DD + d], -kB, kB);
    float s = lc;
    for (int o = 32; o > 0; o >>= 1) s += __shfl_down(s, o);
    if (d == 0) sumlsc[t] = s;
}

// ---------------------------------------------------------------- K1: energy + kl
// t-inner: each thread holds its mu/ls row in sv[64]/muv[64] (long-lived
// read-only regs), walks TCH=16 t's with scalar accumulators.
// Round-9: grid (4,125)=500 blocks capped occupancy at ~2 blocks/CU (18.8%).
// t-replication re-reads are L3-served (FETCH stayed 32MB), so split t finer:
// grid (8,125)=1000 blocks. klt LDS halves to 16.4KB.
__global__ void __launch_bounds__(256, 4)
k_energy_kl(const float* __restrict__ mu, const float* __restrict__ ls,
            const float* __restrict__ st_td, const float* __restrict__ mc_td,
            const float* __restrict__ rs_td, const float* __restrict__ sumlsc,
            float* __restrict__ eT, float* __restrict__ kl_out) {
    const int v  = blockIdx.y * 256 + threadIdx.x;
    const int t0 = blockIdx.x * TCH;

    __shared__ float klt[TCH][257];   // [t_local][v_local], pad -> conflict-free

    // Phase A: load own row, precompute sv / muv / slv
    float sv[DD], muv[DD];
    float slv = 0.f;
    const float* lrow = ls + (size_t)v * DD;
    const float* mrow = mu + (size_t)v * DD;
    #pragma unroll
    for (int q = 0; q < DD / 4; ++q) {
        const float4 l4 = *reinterpret_cast<const float4*>(lrow + q * 4);
        const float4 m4 = *reinterpret_cast<const float4*>(mrow + q * 4);
        const float lf[4] = {l4.x, l4.y, l4.z, l4.w};
        const float mf[4] = {m4.x, m4.y, m4.z, m4.w};
        #pragma unroll
        for (int r = 0; r < 4; ++r) {
            const float lsv = clampf(lf[r], kLSLO, kLSHI);
            slv += lsv;
            sv[q * 4 + r]  = __expf(lsv);
            muv[q * 4 + r] = clampf(mf[r], -kB, kB);
        }
    }

    // Phase B: walk TCH t's, scalar accumulators only
    #pragma unroll 1
    for (int tl = 0; tl < TCH; ++tl) {
        const int t = t0 + tl;
        const float* st_r = st_td + t * DD;   // wave-uniform rows
        const float* mc_r = mc_td + t * DD;
        const float* rs_r = rs_td + t * DD;
        float det = 0.f, ae = 0.f, akl = 0.f;
        #pragma unroll
        for (int dc = 0; dc < 4; ++dc) {
            float prod = 1.f;
            #pragma unroll
            for (int dd = 0; dd < 16; ++dd) {
                const int d = dc * 16 + dd;
                const float st = st_r[d];
                const float mc = mc_r[d];
                const float rs = rs_r[d];
                const float s  = sv[d] + st;
                prod *= s;
                const float diff = muv[d] - mc;
                const float d2   = diff * diff;
                ae  = __builtin_fmaf(d2, __builtin_amdgcn_rcpf(s), ae);
                akl = __builtin_fmaf(sv[d] + d2, rs, akl);
            }
            det += __log2f(prod);
        }
        eT[(size_t)t * V + v] = -0.5f * (det * kLN2 + ae + kDLOG2PI);
        klt[tl][threadIdx.x] = 0.5f * (sumlsc[t] - slv - 64.0f + akl);
    }

    // Phase C: LDS-transposed kl store; each row-write is 64B = full sector.
    __syncthreads();
    const int tc = threadIdx.x & (TCH - 1);
    const int vb = threadIdx.x / TCH;     // 0..15
    #pragma unroll 1
    for (int p = 0; p < 16; ++p) {
        const int vl = p * 16 + vb;
        kl_out[(size_t)(blockIdx.y * 256 + vl) * T + t0 + tc] = klt[tc][vl];
    }
}

// ---------------------------------------------------------------- K2a: online max/sum per column
__global__ void k_colred(const float* __restrict__ eT,
                         float* __restrict__ pmax, float* __restrict__ psum) {
    const int seg = blockIdx.x;   // 0..3, 8000 elems each
    const int t   = blockIdx.y;   // 0..127
    const float* row = eT + (size_t)t * V + seg * 8000;
    float m = -INFINITY, s = 0.f;
    for (int i = threadIdx.x; i < 8000; i += 256) {
        const float e  = row[i];
        const float nm = fmaxf(m, e);
        s = s * __expf(m - nm) + __expf(e - nm);
        m = nm;
    }
    __shared__ float sm[256], ss[256];
    sm[threadIdx.x] = m; ss[threadIdx.x] = s;
    __syncthreads();
    for (int w = 128; w > 0; w >>= 1) {
        if (threadIdx.x < w) {
            const float mA = sm[threadIdx.x], mB = sm[threadIdx.x + w];
            const float nm = fmaxf(mA, mB);
            ss[threadIdx.x] = ss[threadIdx.x] * __expf(mA - nm)
                            + ss[threadIdx.x + w] * __expf(mB - nm);
            sm[threadIdx.x] = nm;
        }
        __syncthreads();
    }
    if (threadIdx.x == 0) { pmax[t * 4 + seg] = sm[0]; psum[t * 4 + seg] = ss[0]; }
}

// ---------------------------------------------------------------- K2b: finalize per-column m, 1/den
__global__ void k_finalize(const float* __restrict__ pmax, const float* __restrict__ psum,
                           float* __restrict__ mrow, float* __restrict__ rden) {
    const int t = threadIdx.x;
    if (t >= T) return;
    float m = -INFINITY, s = 0.f;
    for (int k = 0; k < 4; ++k) {
        const float mB = pmax[t * 4 + k], sB = psum[t * 4 + k];
        const float nm = fmaxf(m, mB);
        s = s * __expf(m - nm) + sB * __expf(mB - nm);
        m = nm;
    }
    mrow[t] = m;
    rden[t] = 1.0f / s;
}

// ---------------------------------------------------------------- K2c: xs = x / den
__global__ void k_scale_x(const float* __restrict__ x, const float* __restrict__ rden,
                          float* __restrict__ xs) {
    const int i = blockIdx.x * 256 + threadIdx.x;
    const int t = i >> 9;    // N = 512
    xs[i] = x[i] * rden[t];
}

// ---------------------------------------------------------------- K3: out = p @ xs  (f32 VALU GEMM)
// Round-9: 43% VALUBusy at 3 blocks/CU -> L2-load-latency exposed. Fixes:
// (a) halve LDS to 16KB (stage 64-t halves) -> ~7 resident blocks/CU;
// (b) explicit 2-deep x prefetch (unroll-2 makes tt&1 static, rule #20).
__global__ void __launch_bounds__(256) k_gemm(const float* __restrict__ eT,
                                              const float* __restrict__ mrow,
                                              const float* __restrict__ xs,
                                              float* __restrict__ out) {
    const int v0 = blockIdx.x * 64;
    const int nbase = blockIdx.y * 128;
    __shared__ float pl[64][64];   // 16 KB, one t-half at a time

    const int va = (threadIdx.x & 15) * 4;  // 4 consecutive v per thread
    const int ng = threadIdx.x >> 4;        // 16 n-groups of 8
    const int nb = nbase + ng * 8;

    float acc[4][8];
    #pragma unroll
    for (int i = 0; i < 4; ++i)
        #pragma unroll
        for (int k = 0; k < 8; ++k) acc[i][k] = 0.f;

    #pragma unroll 1
    for (int h = 0; h < 2; ++h) {
        if (h) __syncthreads();            // previous half's reads done
        #pragma unroll
        for (int i = 0; i < 16; ++i) {
            const int idx = i * 256 + threadIdx.x;
            const int t = idx >> 6, vl = idx & 63;
            const float e = eT[(size_t)(h * 64 + t) * V + v0 + vl];
            pl[t][vl] = __expf(e - mrow[h * 64 + t]);
        }
        __syncthreads();

        const float* xh = xs + (h * 64) * NN + nb;
        float4 xA[2], xB[2];
        xA[0] = *reinterpret_cast<const float4*>(xh);
        xB[0] = *reinterpret_cast<const float4*>(xh + 4);
        xA[1] = *reinterpret_cast<const float4*>(xh + NN);
        xB[1] = *reinterpret_cast<const float4*>(xh + NN + 4);

        #pragma unroll 2
        for (int tt = 0; tt < 64; ++tt) {
            const float4 p4 = *reinterpret_cast<const float4*>(&pl[tt][va]);
            const float4 xa = xA[tt & 1];
            const float4 xb = xB[tt & 1];
            if (tt < 62) {                 // prefetch t+2 into just-consumed slot
                xA[tt & 1] = *reinterpret_cast<const float4*>(xh + (tt + 2) * NN);
                xB[tt & 1] = *reinterpret_cast<const float4*>(xh + (tt + 2) * NN + 4);
            }
            const float pv[4] = {p4.x, p4.y, p4.z, p4.w};
            const float xv[8] = {xa.x, xa.y, xa.z, xa.w, xb.x, xb.y, xb.z, xb.w};
            #pragma unroll
            for (int i = 0; i < 4; ++i)
                #pragma unroll
                for (int k = 0; k < 8; ++k)
                    acc[i][k] = __builtin_fmaf(pv[i], xv[k], acc[i][k]);
        }
    }

    #pragma unroll
    for (int i = 0; i < 4; ++i) {
        f32x4 lo = {acc[i][0], acc[i][1], acc[i][2], acc[i][3]};
        f32x4 hi = {acc[i][4], acc[i][5], acc[i][6], acc[i][7]};
        __builtin_nontemporal_store(lo,
            reinterpret_cast<f32x4*>(&out[(size_t)(v0 + va + i) * NN + nb]));
        __builtin_nontemporal_store(hi,
            reinterpret_cast<f32x4*>(&out[(size_t)(v0 + va + i) * NN + nb + 4]));
    }
}

// ---------------------------------------------------------------- launch
extern "C" void kernel_launch(void* const* d_in, const int* in_sizes, int n_in,
                              void* d_out, int out_size, void* d_ws, size_t ws_size,
                              hipStream_t stream) {
    const float* x    = (const float*)d_in[0];   // (T,N)
    const float* mu   = (const float*)d_in[1];   // (V,D)
    const float* ls   = (const float*)d_in[2];   // (V,D)
    const float* mu_c = (const float*)d_in[3];   // (T,D)
    const float* ls_c = (const float*)d_in[4];   // (T,D)
    // d_in[5] = t scalar: forward values identical for any t; ignored.

    float* out = (float*)d_out;                  // (V,N)
    float* kl  = out + (size_t)V * NN;           // (V,T)

    float* ws      = (float*)d_ws;
    float* eT      = ws;                         // T*V   (energy transposed)
    float* st_td   = eT + (size_t)T * V;         // T*D
    float* mc_td   = st_td + T * DD;             // T*D
    float* rs_td   = mc_td + T * DD;             // T*D
    float* sumlsc  = rs_td + T * DD;             // T
    float* pmax    = sumlsc + T;                 // T*4
    float* psum    = pmax + T * 4;               // T*4
    float* mrow    = psum + T * 4;               // T
    float* rden    = mrow + T;                   // T
    float* xs      = rden + T;                   // T*N

    k_prep<<<T, 64, 0, stream>>>(mu_c, ls_c, st_td, mc_td, rs_td, sumlsc);
    k_energy_kl<<<dim3(T / TCH, V / 256), 256, 0, stream>>>(mu, ls, st_td, mc_td, rs_td, sumlsc, eT, kl);
    k_colred<<<dim3(4, T), 256, 0, stream>>>(eT, pmax, psum);
    k_finalize<<<1, 128, 0, stream>>>(pmax, psum, mrow, rden);
    k_scale_x<<<(T * NN) / 256, 256, 0, stream>>>(x, rden, xs);
    k_gemm<<<dim3(V / 64, 4), 256, 0, stream>>>(eT, mrow, xs, out);
}

// Round 14
// 291.022 us; speedup vs baseline: 1.1877x; 1.1877x over previous
//
#include <hip/hip_runtime.h>
#include <math.h>

#define V 32000
#define T 128
#define DD 64
#define NN 512
#define TCH 16    // t-chunk per k_energy_kl block
#define KPAD 260  // klt row stride: 260%32=4 -> phase-C banks = tc*4+vb, 2-way (free)

typedef float f32x4 __attribute__((ext_vector_type(4)));  // native vec for nontemporal builtin

constexpr float kB     = 1.4142135623730951f;   // sqrt(2)
constexpr float kLSLO  = -2.302585092994046f;   // log(0.1)
constexpr float kLSHI  =  2.302585092994046f;   // log(10)
constexpr float kLN2   =  0.6931471805599453f;
constexpr float kDLOG2PI = 117.6241322501981f;  // 64 * log(2*pi)

__device__ __forceinline__ float clampf(float x, float lo, float hi) {
    return fminf(fmaxf(x, lo), hi);
}

// ---------------------------------------------------------------- K0: prep T-side
// One wave per t: d = lane (D == wave size = 64). Coalesced, shuffle-reduced.
__global__ void k_prep(const float* __restrict__ mu_c, const float* __restrict__ ls_c,
                       float* __restrict__ st_td, float* __restrict__ mc_td,
                       float* __restrict__ rs_td, float* __restrict__ sumlsc) {
    const int t = blockIdx.x;
    const int d = threadIdx.x;
    float lc = clampf(ls_c[t * DD + d], kLSLO, kLSHI);
    const float st = __expf(lc);
    st_td[t * DD + d] = st;
    rs_td[t * DD + d] = 1.0f / st;
    mc_td[t * DD + d] = clampf(mu_c[t * DD + d], -kB, kB);
    float s = lc;
    for (int o = 32; o > 0; o >>= 1) s += __shfl_down(s, o);
    if (d == 0) sumlsc[t] = s;
}

// ---------------------------------------------------------------- K1: energy + kl
// t-inner: each thread holds its mu/ls row in sv[64]/muv[64] (long-lived
// read-only regs), walks TCH=16 t's with scalar accumulators.
// Round-12 failure: __launch_bounds__(256,4) capped VGPR at 64 -> sv/muv
// spilled (FETCH 247MB, WRITE 86MB, VALU 42%). Occupancy must come from the
// GRID (1000 blocks ~ 3.9/CU; 92 VGPR fits 4 blocks/CU in HW), NOT from a
// register cap. Keep (256,2).
__global__ void __launch_bounds__(256, 2)
k_energy_kl(const float* __restrict__ mu, const float* __restrict__ ls,
            const float* __restrict__ st_td, const float* __restrict__ mc_td,
            const float* __restrict__ rs_td, const float* __restrict__ sumlsc,
            float* __restrict__ eT, float* __restrict__ kl_out) {
    const int v  = blockIdx.y * 256 + threadIdx.x;
    const int t0 = blockIdx.x * TCH;

    __shared__ float klt[TCH][KPAD];

    // Phase A: load own row, precompute sv / muv / slv
    float sv[DD], muv[DD];
    float slv = 0.f;
    const float* lrow = ls + (size_t)v * DD;
    const float* mrow = mu + (size_t)v * DD;
    #pragma unroll
    for (int q = 0; q < DD / 4; ++q) {
        const float4 l4 = *reinterpret_cast<const float4*>(lrow + q * 4);
        const float4 m4 = *reinterpret_cast<const float4*>(mrow + q * 4);
        const float lf[4] = {l4.x, l4.y, l4.z, l4.w};
        const float mf[4] = {m4.x, m4.y, m4.z, m4.w};
        #pragma unroll
        for (int r = 0; r < 4; ++r) {
            const float lsv = clampf(lf[r], kLSLO, kLSHI);
            slv += lsv;
            sv[q * 4 + r]  = __expf(lsv);
            muv[q * 4 + r] = clampf(mf[r], -kB, kB);
        }
    }

    // Phase B: walk TCH t's, scalar accumulators only
    #pragma unroll 1
    for (int tl = 0; tl < TCH; ++tl) {
        const int t = t0 + tl;
        const float* st_r = st_td + t * DD;   // wave-uniform rows
        const float* mc_r = mc_td + t * DD;
        const float* rs_r = rs_td + t * DD;
        float det = 0.f, ae = 0.f, akl = 0.f;
        #pragma unroll
        for (int dc = 0; dc < 4; ++dc) {
            float prod = 1.f;
            #pragma unroll
            for (int dd = 0; dd < 16; ++dd) {
                const int d = dc * 16 + dd;
                const float st = st_r[d];
                const float mc = mc_r[d];
                const float rs = rs_r[d];
                const float s  = sv[d] + st;
                prod *= s;
                const float diff = muv[d] - mc;
                const float d2   = diff * diff;
                ae  = __builtin_fmaf(d2, __builtin_amdgcn_rcpf(s), ae);
                akl = __builtin_fmaf(sv[d] + d2, rs, akl);
            }
            det += __log2f(prod);
        }
        eT[(size_t)t * V + v] = -0.5f * (det * kLN2 + ae + kDLOG2PI);
        klt[tl][threadIdx.x] = 0.5f * (sumlsc[t] - slv - 64.0f + akl);
    }

    // Phase C: LDS-transposed kl store; each 16-lane group writes one v-row's
    // 16 t's = 64B contiguous.
    __syncthreads();
    const int tc = threadIdx.x & (TCH - 1);
    const int vb = threadIdx.x / TCH;     // 0..15
    #pragma unroll 1
    for (int p = 0; p < 16; ++p) {
        const int vl = p * 16 + vb;
        kl_out[(size_t)(blockIdx.y * 256 + vl) * T + t0 + tc] = klt[tc][vl];
    }
}

// ---------------------------------------------------------------- K2a: online max/sum per column
__global__ void k_colred(const float* __restrict__ eT,
                         float* __restrict__ pmax, float* __restrict__ psum) {
    const int seg = blockIdx.x;   // 0..3, 8000 elems each
    const int t   = blockIdx.y;   // 0..127
    const float* row = eT + (size_t)t * V + seg * 8000;
    float m = -INFINITY, s = 0.f;
    for (int i = threadIdx.x; i < 8000; i += 256) {
        const float e  = row[i];
        const float nm = fmaxf(m, e);
        s = s * __expf(m - nm) + __expf(e - nm);
        m = nm;
    }
    __shared__ float sm[256], ss[256];
    sm[threadIdx.x] = m; ss[threadIdx.x] = s;
    __syncthreads();
    for (int w = 128; w > 0; w >>= 1) {
        if (threadIdx.x < w) {
            const float mA = sm[threadIdx.x], mB = sm[threadIdx.x + w];
            const float nm = fmaxf(mA, mB);
            ss[threadIdx.x] = ss[threadIdx.x] * __expf(mA - nm)
                            + ss[threadIdx.x + w] * __expf(mB - nm);
            sm[threadIdx.x] = nm;
        }
        __syncthreads();
    }
    if (threadIdx.x == 0) { pmax[t * 4 + seg] = sm[0]; psum[t * 4 + seg] = ss[0]; }
}

// ---------------------------------------------------------------- K2b: finalize per-column m, 1/den
__global__ void k_finalize(const float* __restrict__ pmax, const float* __restrict__ psum,
                           float* __restrict__ mrow, float* __restrict__ rden) {
    const int t = threadIdx.x;
    if (t >= T) return;
    float m = -INFINITY, s = 0.f;
    for (int k = 0; k < 4; ++k) {
        const float mB = pmax[t * 4 + k], sB = psum[t * 4 + k];
        const float nm = fmaxf(m, mB);
        s = s * __expf(m - nm) + sB * __expf(mB - nm);
        m = nm;
    }
    mrow[t] = m;
    rden[t] = 1.0f / s;
}

// ---------------------------------------------------------------- K2c: xs = x / den
__global__ void k_scale_x(const float* __restrict__ x, const float* __restrict__ rden,
                          float* __restrict__ xs) {
    const int i = blockIdx.x * 256 + threadIdx.x;
    const int t = i >> 9;    // N = 512
    xs[i] = x[i] * rden[t];
}

// ---------------------------------------------------------------- K3: out = p @ xs  (f32 VALU GEMM)
// 16KB LDS (64-t halves) + 2-deep x prefetch (unroll-2 keeps tt&1 static).
__global__ void __launch_bounds__(256) k_gemm(const float* __restrict__ eT,
                                              const float* __restrict__ mrow,
                                              const float* __restrict__ xs,
                                              float* __restrict__ out) {
    const int v0 = blockIdx.x * 64;
    const int nbase = blockIdx.y * 128;
    __shared__ float pl[64][64];   // 16 KB, one t-half at a time

    const int va = (threadIdx.x & 15) * 4;  // 4 consecutive v per thread
    const int ng = threadIdx.x >> 4;        // 16 n-groups of 8
    const int nb = nbase + ng * 8;

    float acc[4][8];
    #pragma unroll
    for (int i = 0; i < 4; ++i)
        #pragma unroll
        for (int k = 0; k < 8; ++k) acc[i][k] = 0.f;

    #pragma unroll 1
    for (int h = 0; h < 2; ++h) {
        if (h) __syncthreads();            // previous half's reads done
        #pragma unroll
        for (int i = 0; i < 16; ++i) {
            const int idx = i * 256 + threadIdx.x;
            const int t = idx >> 6, vl = idx & 63;
            const float e = eT[(size_t)(h * 64 + t) * V + v0 + vl];
            pl[t][vl] = __expf(e - mrow[h * 64 + t]);
        }
        __syncthreads();

        const float* xh = xs + (h * 64) * NN + nb;
        float4 xA[2], xB[2];
        xA[0] = *reinterpret_cast<const float4*>(xh);
        xB[0] = *reinterpret_cast<const float4*>(xh + 4);
        xA[1] = *reinterpret_cast<const float4*>(xh + NN);
        xB[1] = *reinterpret_cast<const float4*>(xh + NN + 4);

        #pragma unroll 2
        for (int tt = 0; tt < 64; ++tt) {
            const float4 p4 = *reinterpret_cast<const float4*>(&pl[tt][va]);
            const float4 xa = xA[tt & 1];
            const float4 xb = xB[tt & 1];
            if (tt < 62) {                 // prefetch t+2 into just-consumed slot
                xA[tt & 1] = *reinterpret_cast<const float4*>(xh + (tt + 2) * NN);
                xB[tt & 1] = *reinterpret_cast<const float4*>(xh + (tt + 2) * NN + 4);
            }
            const float pv[4] = {p4.x, p4.y, p4.z, p4.w};
            const float xv[8] = {xa.x, xa.y, xa.z, xa.w, xb.x, xb.y, xb.z, xb.w};
            #pragma unroll
            for (int i = 0; i < 4; ++i)
                #pragma unroll
                for (int k = 0; k < 8; ++k)
                    acc[i][k] = __builtin_fmaf(pv[i], xv[k], acc[i][k]);
        }
    }

    #pragma unroll
    for (int i = 0; i < 4; ++i) {
        f32x4 lo = {acc[i][0], acc[i][1], acc[i][2], acc[i][3]};
        f32x4 hi = {acc[i][4], acc[i][5], acc[i][6], acc[i][7]};
        __builtin_nontemporal_store(lo,
            reinterpret_cast<f32x4*>(&out[(size_t)(v0 + va + i) * NN + nb]));
        __builtin_nontemporal_store(hi,
            reinterpret_cast<f32x4*>(&out[(size_t)(v0 + va + i) * NN + nb + 4]));
    }
}

// ---------------------------------------------------------------- launch
extern "C" void kernel_launch(void* const* d_in, const int* in_sizes, int n_in,
                              void* d_out, int out_size, void* d_ws, size_t ws_size,
                              hipStream_t stream) {
    const float* x    = (const float*)d_in[0];   // (T,N)
    const float* mu   = (const float*)d_in[1];   // (V,D)
    const float* ls   = (const float*)d_in[2];   // (V,D)
    const float* mu_c = (const float*)d_in[3];   // (T,D)
    const float* ls_c = (const float*)d_in[4];   // (T,D)
    // d_in[5] = t scalar: forward values identical for any t; ignored.

    float* out = (float*)d_out;                  // (V,N)
    float* kl  = out + (size_t)V * NN;           // (V,T)

    float* ws      = (float*)d_ws;
    float* eT      = ws;                         // T*V   (energy transposed)
    float* st_td   = eT + (size_t)T * V;         // T*D
    float* mc_td   = st_td + T * DD;             // T*D
    float* rs_td   = mc_td + T * DD;             // T*D
    float* sumlsc  = rs_td + T * DD;             // T
    float* pmax    = sumlsc + T;                 // T*4
    float* psum    = pmax + T * 4;               // T*4
    float* mrow    = psum + T * 4;               // T
    float* rden    = mrow + T;                   // T
    float* xs      = rden + T;                   // T*N

    k_prep<<<T, 64, 0, stream>>>(mu_c, ls_c, st_td, mc_td, rs_td, sumlsc);
    k_energy_kl<<<dim3(T / TCH, V / 256), 256, 0, stream>>>(mu, ls, st_td, mc_td, rs_td, sumlsc, eT, kl);
    k_colred<<<dim3(4, T), 256, 0, stream>>>(eT, pmax, psum);
    k_finalize<<<1, 128, 0, stream>>>(pmax, psum, mrow, rden);
    k_scale_x<<<(T * NN) / 256, 256, 0, stream>>>(x, rden, xs);
    k_gemm<<<dim3(V / 64, 4), 256, 0, stream>>>(eT, mrow, xs, out);
}